// Round 1
// baseline (578.887 us; speedup 1.0000x reference)
//
#include <hip/hip_runtime.h>

#define T_PATCH 256
#define C_DIM   768
#define N_B     8
#define N_N     32

// ---------------- kernel 0: tar feature inverse norms ----------------
__global__ void tar_norm_kernel(const float* __restrict__ tar,
                                float* __restrict__ tarinv) {
    int b = blockIdx.x;
    int t = threadIdx.x;
    const float* p = tar + (size_t)b * C_DIM * T_PATCH + t;
    float ss = 0.f;
    for (int c = 0; c < C_DIM; ++c) {
        float v = p[c * T_PATCH];
        ss = fmaf(v, v, ss);
    }
    tarinv[b * T_PATCH + t] = 1.f / fmaxf(sqrtf(ss), 1e-12f);
}

// ---------------- kernel 1: per-(b,n) similarity + matching ----------------
__launch_bounds__(1024, 4)
__global__ void sim_kernel(const float* __restrict__ src_feats,
                           const float* __restrict__ tar_feat,
                           const float* __restrict__ src_masks,
                           const float* __restrict__ tar_mask,
                           const float* __restrict__ tarinv,
                           float* __restrict__ w_score,
                           float* __restrict__ w_mall,
                           float* __restrict__ w_savg,
                           int*   __restrict__ w_idx,
                           float* __restrict__ out) {
    __shared__ float tarT[8][T_PATCH];
    __shared__ float srcT[8][T_PATCH];
    __shared__ float sq[1024];
    __shared__ float colv[16 * T_PATCH];   // [wave][s]
    __shared__ int   coli[16 * T_PATCH];
    __shared__ float sc_t2s[T_PATCH];
    __shared__ int   ix_t2s[T_PATCH];
    __shared__ float sc_s2t[T_PATCH];
    __shared__ int   ix_s2t[T_PATCH];
    __shared__ float invT[T_PATCH], invS[T_PATCH], tm[T_PATCH], sm[T_PATCH];
    __shared__ float red[8];

    int bn  = blockIdx.x;
    int b   = bn >> 5;
    int tid = threadIdx.x;
    int tx = tid & 31, ty = tid >> 5;
    int t0 = ty * 8, s0 = tx * 8;

    const float* tb = tar_feat + (size_t)b  * C_DIM * T_PATCH;
    const float* sb = src_feats + (size_t)bn * C_DIM * T_PATCH;

    if (tid < T_PATCH) {
        invT[tid] = tarinv[b * T_PATCH + tid];
        tm[tid]   = tar_mask[b * T_PATCH + tid];
        sm[tid]   = src_masks[bn * T_PATCH + tid];
    }

    float acc[8][8];
    #pragma unroll
    for (int i = 0; i < 8; ++i)
        #pragma unroll
        for (int j = 0; j < 8; ++j) acc[i][j] = 0.f;

    float ssq = 0.f;
    int r = tid >> 8, col = tid & 255;

    for (int c0 = 0; c0 < C_DIM; c0 += 8) {
        __syncthreads();
        tarT[r][col]     = tb[(c0 + r) * T_PATCH + col];
        tarT[r + 4][col] = tb[(c0 + r + 4) * T_PATCH + col];
        float v1 = sb[(c0 + r) * T_PATCH + col];
        float v2 = sb[(c0 + r + 4) * T_PATCH + col];
        srcT[r][col] = v1; srcT[r + 4][col] = v2;
        ssq = fmaf(v1, v1, ssq);
        ssq = fmaf(v2, v2, ssq);
        __syncthreads();
        #pragma unroll
        for (int cc = 0; cc < 8; ++cc) {
            float4 a0 = *(const float4*)&tarT[cc][t0];
            float4 a1 = *(const float4*)&tarT[cc][t0 + 4];
            float4 b0 = *(const float4*)&srcT[cc][s0];
            float4 b1 = *(const float4*)&srcT[cc][s0 + 4];
            float av[8] = {a0.x, a0.y, a0.z, a0.w, a1.x, a1.y, a1.z, a1.w};
            float bv[8] = {b0.x, b0.y, b0.z, b0.w, b1.x, b1.y, b1.z, b1.w};
            #pragma unroll
            for (int i = 0; i < 8; ++i)
                #pragma unroll
                for (int j = 0; j < 8; ++j)
                    acc[i][j] = fmaf(av[i], bv[j], acc[i][j]);
        }
    }

    // src inverse norms (sum of squares gathered during staging)
    sq[tid] = ssq;
    __syncthreads();
    if (tid < T_PATCH) {
        float tot = sq[tid] + sq[tid + 256] + sq[tid + 512] + sq[tid + 768];
        invS[tid] = 1.f / fmaxf(sqrtf(tot), 1e-12f);
    }
    __syncthreads();

    // normalize + mask + threshold (values become 0 or >= 0.05)
    #pragma unroll
    for (int i = 0; i < 8; ++i) {
        int t = t0 + i;
        float it = invT[t];
        float mt = tm[t];
        #pragma unroll
        for (int j = 0; j < 8; ++j) {
            int s = s0 + j;
            float v = acc[i][j] * it * invS[s];
            bool keep = (mt != 0.f) && (sm[s] != 0.f) && (v >= 0.05f);
            acc[i][j] = keep ? v : 0.f;
        }
    }

    // ---- t2s: max/argmax over s (rows). Row t spans tx=0..31 (half-wave).
    #pragma unroll
    for (int i = 0; i < 8; ++i) {
        float bv = -1.f; int bi = 0;
        #pragma unroll
        for (int j = 0; j < 8; ++j) {
            float v = acc[i][j];
            if (v > bv) { bv = v; bi = s0 + j; }
        }
        #pragma unroll
        for (int off = 1; off < 32; off <<= 1) {
            float ov = __shfl_xor(bv, off, 64);
            int   oi = __shfl_xor(bi, off, 64);
            if (ov > bv || (ov == bv && oi < bi)) { bv = ov; bi = oi; }
        }
        if (tx == 0) { sc_t2s[t0 + i] = bv; ix_t2s[t0 + i] = bi; }
    }

    // ---- s2t: max/argmax over t (cols). Combine lane^32 then across waves.
    {
        float cvv[8]; int cvi[8];
        #pragma unroll
        for (int j = 0; j < 8; ++j) {
            float bv = -1.f; int bi = 0;
            #pragma unroll
            for (int i = 0; i < 8; ++i) {
                float v = acc[i][j];
                if (v > bv) { bv = v; bi = t0 + i; }
            }
            float ov = __shfl_xor(bv, 32, 64);
            int   oi = __shfl_xor(bi, 32, 64);
            if (ov > bv || (ov == bv && oi < bi)) { bv = ov; bi = oi; }
            cvv[j] = bv; cvi[j] = bi;
        }
        if ((tid & 63) < 32) {
            int w = tid >> 6;
            *(float4*)&colv[w * T_PATCH + s0]     = *(float4*)&cvv[0];
            *(float4*)&colv[w * T_PATCH + s0 + 4] = *(float4*)&cvv[4];
            *(int4*)&coli[w * T_PATCH + s0]       = *(int4*)&cvi[0];
            *(int4*)&coli[w * T_PATCH + s0 + 4]   = *(int4*)&cvi[4];
        }
    }
    __syncthreads();
    if (tid < T_PATCH) {
        float bv = -1.f; int bi = 0;
        for (int w = 0; w < 16; ++w) {
            float ov = colv[w * T_PATCH + tid];
            int   oi = coli[w * T_PATCH + tid];
            if (ov > bv || (ov == bv && oi < bi)) { bv = ov; bi = oi; }
        }
        sc_s2t[tid] = bv; ix_s2t[tid] = bi;
    }
    __syncthreads();

    // ---- per-t match decision
    float cnt = 0.f, svs = 0.f;
    if (tid < T_PATCH) {
        int t = tid;
        float st2s = sc_t2s[t];
        int   i    = ix_t2s[t];
        bool msim = st2s >= 0.05f;
        int is2s = ix_s2t[i];
        int dw = (is2s & 15) - (t & 15);
        int dh = (is2s >> 4) - (t >> 4);
        bool cyc = (dw * dw + dh * dh <= 4) && (sc_s2t[i] >= 0.05f);
        float mnz = tm[t] * sm[i] *
                    ((ix_s2t[t] != 0) ? 1.f : 0.f) *
                    ((i != 0) ? 1.f : 0.f);
        float mall = (msim && cyc) ? mnz : 0.f;
        w_score[bn * T_PATCH + t] = st2s;
        w_mall[bn * T_PATCH + t]  = mall;
        w_idx[bn * T_PATCH + t]   = i;
        cnt = mall;
        svs = st2s * mall;
    }
    #pragma unroll
    for (int off = 1; off < 64; off <<= 1) {
        cnt += __shfl_xor(cnt, off, 64);
        svs += __shfl_xor(svs, off, 64);
    }
    if (tid < T_PATCH && (tid & 63) == 0) {
        red[(tid >> 6) * 2]     = cnt;
        red[(tid >> 6) * 2 + 1] = svs;
    }
    __syncthreads();
    if (tid == 0) {
        float c = red[0] + red[2] + red[4] + red[6];
        float s = red[1] + red[3] + red[5] + red[7];
        w_savg[bn] = (c > 0.f) ? (s * (1.f / 256.f)) : 0.f;
        out[51280 + bn] = c;   // match_counts
    }
}

// ---------------- kernel 2: top-k + formatting ----------------
__global__ void final_kernel(const float* __restrict__ w_score,
                             const float* __restrict__ w_mall,
                             const float* __restrict__ w_savg,
                             const int*   __restrict__ w_idx,
                             float* __restrict__ out) {
    int b = blockIdx.x, tid = threadIdx.x;
    __shared__ float savg[32];
    __shared__ int   topid[5];
    __shared__ float topv[5];
    if (tid < 32) savg[tid] = w_savg[b * 32 + tid];
    __syncthreads();
    if (tid == 0) {
        unsigned used = 0;
        for (int k = 0; k < 5; ++k) {
            float bv = -1e30f; int bi = 0;
            for (int n = 0; n < 32; ++n) {
                if (!((used >> n) & 1u) && savg[n] > bv) { bv = savg[n]; bi = n; }
            }
            used |= (1u << bi);
            topid[k] = bi; topv[k] = bv;
        }
    }
    __syncthreads();
    if (tid < 5) {
        out[b * 5 + tid]      = (float)topid[tid];   // id_src
        out[40 + b * 5 + tid] = topv[tid];           // score_src
    }
    int t = tid;
    for (int k = 0; k < 5; ++k) {
        int bn = b * 32 + topid[k];
        float sc = w_score[bn * 256 + t];
        float ma = w_mall[bn * 256 + t];
        int   ii = w_idx[bn * 256 + t];
        int o = (b * 5 + k) * 256 + t;
        out[80 + o] = sc;                            // score_pts
        bool nz = (ma != 0.f);
        out[10320 + 2 * o]     = nz ? (float)(t & 15)  : -1.f;  // tar_pts w
        out[10320 + 2 * o + 1] = nz ? (float)(t >> 4)  : -1.f;  // tar_pts h
        out[30800 + 2 * o]     = nz ? (float)(ii & 15) : -1.f;  // src_pts w
        out[30800 + 2 * o + 1] = nz ? (float)(ii >> 4) : -1.f;  // src_pts h
    }
}

extern "C" void kernel_launch(void* const* d_in, const int* in_sizes, int n_in,
                              void* d_out, int out_size, void* d_ws, size_t ws_size,
                              hipStream_t stream) {
    const float* src_feats = (const float*)d_in[0];
    const float* tar_feat  = (const float*)d_in[1];
    const float* src_masks = (const float*)d_in[2];
    const float* tar_mask  = (const float*)d_in[3];
    float* out = (float*)d_out;

    float* ws       = (float*)d_ws;
    float* w_tarinv = ws;                       // 2048
    float* w_score  = w_tarinv + 2048;          // 65536
    float* w_mall   = w_score + 65536;          // 65536
    float* w_savg   = w_mall + 65536;           // 256
    int*   w_idx    = (int*)(w_savg + 256);     // 65536

    tar_norm_kernel<<<N_B, 256, 0, stream>>>(tar_feat, w_tarinv);
    sim_kernel<<<N_B * N_N, 1024, 0, stream>>>(src_feats, tar_feat, src_masks,
                                               tar_mask, w_tarinv,
                                               w_score, w_mall, w_savg, w_idx, out);
    final_kernel<<<N_B, 256, 0, stream>>>(w_score, w_mall, w_savg, w_idx, out);
}